// Round 3
// baseline (727.380 us; speedup 1.0000x reference)
//
#include <hip/hip_runtime.h>
#include <hip/hip_bf16.h>

#define N_NODES 50000
#define N_EDGES 800000
#define DD 64
#define NGRAPH 64

__device__ __forceinline__ float swish_f(float v) {
    return v / (1.0f + __expf(-v));
}

// ---------------- scatter: agg[col[e]] += edge_attr[e] ----------------
// 16 lanes per edge, float4 each. tid consecutive -> coalesced edge_attr reads.
// unsafeAtomicAdd -> global_atomic_add_f32 (no-return HW atomic at L2),
// NOT the CAS loop that plain atomicAdd(float*) emits (R1: 683us, 819MB WRITE_SIZE).
__global__ __launch_bounds__(256) void scatter_kernel(
    const float* __restrict__ edge_attr,
    const int* __restrict__ col,
    float* __restrict__ agg)
{
    const int tid = blockIdx.x * 256 + threadIdx.x;
    const int e = tid >> 4;
    const int q = (tid & 15) << 2;
    const int c = col[e];
    const float4 v = *reinterpret_cast<const float4*>(edge_attr + (size_t)e * DD + q);
    float* dst = agg + (size_t)c * DD + q;
    unsafeAtomicAdd(dst + 0, v.x);
    unsafeAtomicAdd(dst + 1, v.y);
    unsafeAtomicAdd(dst + 2, v.z);
    unsafeAtomicAdd(dst + 3, v.w);
}

// ---------------- fused 2-layer MLP ----------------
// lane = node (64 nodes/block), wave = 16-wide output chunk.
// W accesses are wave-uniform -> s_load broadcast (no LDS for weights).
__global__ __launch_bounds__(256) void mlp_kernel(
    const float* __restrict__ x,
    const float* __restrict__ agg,
    const float* __restrict__ u,
    const int* __restrict__ batch,
    const float* __restrict__ W1,
    const float* __restrict__ b1,
    const float* __restrict__ W2,
    const float* __restrict__ b2,
    float* __restrict__ out)
{
    __shared__ float sh[64][65];   // padded: bank = (lane + k) % 32, conflict-free
    const int lane = threadIdx.x & 63;
    const int j0 = __builtin_amdgcn_readfirstlane((threadIdx.x >> 6) << 4);
    const int node = blockIdx.x * 64 + lane;
    const bool valid = node < N_NODES;
    const int nc = valid ? node : (N_NODES - 1);

    float acc[16];
    #pragma unroll
    for (int j = 0; j < 16; ++j) acc[j] = b1[j0 + j];

    const float* __restrict__ row0 = x + (size_t)nc * DD;
    const float* __restrict__ row1 = agg + (size_t)nc * DD;
    const float* __restrict__ row2 = u + (size_t)batch[nc] * DD;

    #pragma unroll
    for (int s = 0; s < 3; ++s) {
        const float* __restrict__ row = (s == 0) ? row0 : (s == 1) ? row1 : row2;
        const float* __restrict__ w = W1 + (size_t)s * 64 * 64 + j0;
        for (int kk = 0; kk < 64; kk += 4) {
            const float4 v = *reinterpret_cast<const float4*>(row + kk);
            #pragma unroll
            for (int i = 0; i < 4; ++i) {
                const float iv = (i == 0) ? v.x : (i == 1) ? v.y : (i == 2) ? v.z : v.w;
                const float* __restrict__ wr = w + (size_t)(kk + i) * 64;
                #pragma unroll
                for (int j = 0; j < 16; ++j)
                    acc[j] += iv * wr[j];
            }
        }
    }

    #pragma unroll
    for (int j = 0; j < 16; ++j)
        sh[lane][j0 + j] = swish_f(acc[j]);

    __syncthreads();

    float acc2[16];
    #pragma unroll
    for (int j = 0; j < 16; ++j) acc2[j] = b2[j0 + j];
    for (int k = 0; k < 64; ++k) {
        const float hk = sh[lane][k];
        const float* __restrict__ wr = W2 + (size_t)k * 64 + j0;
        #pragma unroll
        for (int j = 0; j < 16; ++j)
            acc2[j] += hk * wr[j];
    }

    if (valid) {
        float* o = out + (size_t)node * DD + j0;
        #pragma unroll
        for (int j = 0; j < 16; j += 4) {
            float4 r;
            r.x = swish_f(acc2[j + 0]);
            r.y = swish_f(acc2[j + 1]);
            r.z = swish_f(acc2[j + 2]);
            r.w = swish_f(acc2[j + 3]);
            *reinterpret_cast<float4*>(o + j) = r;
        }
    }
}

extern "C" void kernel_launch(void* const* d_in, const int* in_sizes, int n_in,
                              void* d_out, int out_size, void* d_ws, size_t ws_size,
                              hipStream_t stream) {
    const float* x         = (const float*)d_in[0];
    const int*   ei        = (const int*)d_in[1];
    const float* edge_attr = (const float*)d_in[2];
    const float* u         = (const float*)d_in[3];
    const int*   batch     = (const int*)d_in[4];
    const float* W1        = (const float*)d_in[5];
    const float* b1        = (const float*)d_in[6];
    const float* W2        = (const float*)d_in[7];
    const float* b2        = (const float*)d_in[8];
    float* out = (float*)d_out;
    float* agg = (float*)d_ws;

    // zero the aggregation buffer every call (ws is not re-poisoned between replays)
    hipMemsetAsync(agg, 0, (size_t)N_NODES * DD * sizeof(float), stream);

    // col = edge_index[1] -> second row
    scatter_kernel<<<(N_EDGES * 16) / 256, 256, 0, stream>>>(edge_attr, ei + N_EDGES, agg);

    mlp_kernel<<<(N_NODES + 63) / 64, 256, 0, stream>>>(x, agg, u, batch, W1, b1, W2, b2, out);
}

// Round 4
// 262.924 us; speedup vs baseline: 2.7665x; 2.7665x over previous
//
#include <hip/hip_runtime.h>
#include <hip/hip_bf16.h>

#define N_NODES 50000
#define N_EDGES 800000
#define DD 64
#define NGRAPH 64

// R1/R3 evidence: 51.2M scalar f32 device-scope atomics run at ~75 G/s (682us,
// WRITE_SIZE=16B/atomic) regardless of atomicAdd vs unsafeAtomicAdd -> atomic
// op-rate-bound. This version removes FP atomics entirely via per-call CSR:
//   memset(offs) -> hist (int atomics, 0.8M) -> scan -> fill (int atomics, 0.8M)
//   -> gather-aggregate (coalesced float4 reads, shuffle reduce, plain stores)
//   -> fused MLP.
//
// ws layout: agg[50000*64] f32 | offs[50000] i32 | eids[800000] i32  (~15.5 MB)

__device__ __forceinline__ float swish_f(float v) {
    return v / (1.0f + __expf(-v));
}

__global__ __launch_bounds__(256) void hist_kernel(
    const int* __restrict__ col, int* __restrict__ cnt)
{
    const int e = blockIdx.x * 256 + threadIdx.x;
    if (e < N_EDGES) atomicAdd(&cnt[col[e]], 1);
}

// in-place counts -> exclusive starts. single block, 1024 threads, chunked.
__global__ __launch_bounds__(1024) void scan_kernel(int* __restrict__ offs)
{
    const int T = 1024;
    const int C = (N_NODES + T - 1) / T;   // 49
    const int t = threadIdx.x;
    const int base = t * C;

    int s = 0;
    for (int i = 0; i < C; ++i) {
        const int idx = base + i;
        if (idx < N_NODES) s += offs[idx];
    }
    __shared__ int sm[T];
    sm[t] = s;
    __syncthreads();
    for (int d = 1; d < T; d <<= 1) {
        const int v = (t >= d) ? sm[t - d] : 0;
        __syncthreads();
        sm[t] += v;
        __syncthreads();
    }
    int run = (t == 0) ? 0 : sm[t - 1];
    for (int i = 0; i < C; ++i) {
        const int idx = base + i;
        if (idx < N_NODES) {
            const int c = offs[idx];
            offs[idx] = run;
            run += c;
        }
    }
}

// offs[n] = start(n) on entry; on exit offs[n] = start(n)+count(n) = start(n+1).
// gather then uses beg = (n==0)?0:offs[n-1], end = offs[n].
__global__ __launch_bounds__(256) void fill_kernel(
    const int* __restrict__ col, int* __restrict__ offs, int* __restrict__ eids)
{
    const int e = blockIdx.x * 256 + threadIdx.x;
    if (e < N_EDGES) {
        const int c = col[e];
        const int pos = atomicAdd(&offs[c], 1);
        eids[pos] = e;
    }
}

// one wave per node: 16 lanes x float4 cover 64 dims; 4 edge-slots in parallel.
__global__ __launch_bounds__(256) void agg_kernel(
    const float* __restrict__ edge_attr,
    const int* __restrict__ offs,
    const int* __restrict__ eids,
    float* __restrict__ agg)
{
    const int n = (blockIdx.x * 256 + threadIdx.x) >> 6;
    if (n >= N_NODES) return;
    const int lane = threadIdx.x & 63;
    const int q = lane & 15;      // dim quad: dims [4q, 4q+4)
    const int slot = lane >> 4;   // edge slot 0..3
    const int beg = (n == 0) ? 0 : offs[n - 1];
    const int deg = offs[n] - beg;

    float4 acc = make_float4(0.f, 0.f, 0.f, 0.f);
    for (int i = slot; i < deg; i += 4) {
        const int eid = eids[beg + i];
        const float4 v = *reinterpret_cast<const float4*>(
            edge_attr + (size_t)eid * DD + q * 4);
        acc.x += v.x; acc.y += v.y; acc.z += v.z; acc.w += v.w;
    }
    #pragma unroll
    for (int m = 16; m < 64; m <<= 1) {
        acc.x += __shfl_xor(acc.x, m, 64);
        acc.y += __shfl_xor(acc.y, m, 64);
        acc.z += __shfl_xor(acc.z, m, 64);
        acc.w += __shfl_xor(acc.w, m, 64);
    }
    if (slot == 0)
        *reinterpret_cast<float4*>(agg + (size_t)n * DD + q * 4) = acc;
}

// ---------------- fused 2-layer MLP (unchanged from R1, ~35us) ----------------
__global__ __launch_bounds__(256) void mlp_kernel(
    const float* __restrict__ x,
    const float* __restrict__ agg,
    const float* __restrict__ u,
    const int* __restrict__ batch,
    const float* __restrict__ W1,
    const float* __restrict__ b1,
    const float* __restrict__ W2,
    const float* __restrict__ b2,
    float* __restrict__ out)
{
    __shared__ float sh[64][65];
    const int lane = threadIdx.x & 63;
    const int j0 = __builtin_amdgcn_readfirstlane((threadIdx.x >> 6) << 4);
    const int node = blockIdx.x * 64 + lane;
    const bool valid = node < N_NODES;
    const int nc = valid ? node : (N_NODES - 1);

    float acc[16];
    #pragma unroll
    for (int j = 0; j < 16; ++j) acc[j] = b1[j0 + j];

    const float* __restrict__ row0 = x + (size_t)nc * DD;
    const float* __restrict__ row1 = agg + (size_t)nc * DD;
    const float* __restrict__ row2 = u + (size_t)batch[nc] * DD;

    #pragma unroll
    for (int s = 0; s < 3; ++s) {
        const float* __restrict__ row = (s == 0) ? row0 : (s == 1) ? row1 : row2;
        const float* __restrict__ w = W1 + (size_t)s * 64 * 64 + j0;
        for (int kk = 0; kk < 64; kk += 4) {
            const float4 v = *reinterpret_cast<const float4*>(row + kk);
            #pragma unroll
            for (int i = 0; i < 4; ++i) {
                const float iv = (i == 0) ? v.x : (i == 1) ? v.y : (i == 2) ? v.z : v.w;
                const float* __restrict__ wr = w + (size_t)(kk + i) * 64;
                #pragma unroll
                for (int j = 0; j < 16; ++j)
                    acc[j] += iv * wr[j];
            }
        }
    }

    #pragma unroll
    for (int j = 0; j < 16; ++j)
        sh[lane][j0 + j] = swish_f(acc[j]);

    __syncthreads();

    float acc2[16];
    #pragma unroll
    for (int j = 0; j < 16; ++j) acc2[j] = b2[j0 + j];
    for (int k = 0; k < 64; ++k) {
        const float hk = sh[lane][k];
        const float* __restrict__ wr = W2 + (size_t)k * 64 + j0;
        #pragma unroll
        for (int j = 0; j < 16; ++j)
            acc2[j] += hk * wr[j];
    }

    if (valid) {
        float* o = out + (size_t)node * DD + j0;
        #pragma unroll
        for (int j = 0; j < 16; j += 4) {
            float4 r;
            r.x = swish_f(acc2[j + 0]);
            r.y = swish_f(acc2[j + 1]);
            r.z = swish_f(acc2[j + 2]);
            r.w = swish_f(acc2[j + 3]);
            *reinterpret_cast<float4*>(o + j) = r;
        }
    }
}

extern "C" void kernel_launch(void* const* d_in, const int* in_sizes, int n_in,
                              void* d_out, int out_size, void* d_ws, size_t ws_size,
                              hipStream_t stream) {
    const float* x         = (const float*)d_in[0];
    const int*   ei        = (const int*)d_in[1];
    const float* edge_attr = (const float*)d_in[2];
    const float* u         = (const float*)d_in[3];
    const int*   batch     = (const int*)d_in[4];
    const float* W1        = (const float*)d_in[5];
    const float* b1        = (const float*)d_in[6];
    const float* W2        = (const float*)d_in[7];
    const float* b2        = (const float*)d_in[8];
    float* out = (float*)d_out;

    float* agg = (float*)d_ws;
    int* offs  = (int*)((char*)d_ws + (size_t)N_NODES * DD * sizeof(float));
    int* eids  = offs + N_NODES;
    const int* col = ei + N_EDGES;   // edge_index[1]

    // counts must start at zero every call (ws not re-poisoned between replays)
    hipMemsetAsync(offs, 0, (size_t)N_NODES * sizeof(int), stream);

    hist_kernel<<<(N_EDGES + 255) / 256, 256, 0, stream>>>(col, offs);
    scan_kernel<<<1, 1024, 0, stream>>>(offs);
    fill_kernel<<<(N_EDGES + 255) / 256, 256, 0, stream>>>(col, offs, eids);
    agg_kernel<<<(N_NODES + 3) / 4, 256, 0, stream>>>(edge_attr, offs, eids, agg);

    mlp_kernel<<<(N_NODES + 63) / 64, 256, 0, stream>>>(x, agg, u, batch, W1, b1, W2, b2, out);
}

// Round 5
// 258.870 us; speedup vs baseline: 2.8098x; 1.0157x over previous
//
#include <hip/hip_runtime.h>
#include <hip/hip_bf16.h>

#define N_NODES 50000
#define N_EDGES 800000
#define DD 64
#define NGRAPH 64

// R1/R3: 51.2M f32 device atomics = 682us (op-rate-bound) -> CSR+gather (R4: 263us).
// R4: hipMemsetAsync(200KB) -> rocclr fillBufferAligned = 117us (!!) at 1.8GB/s,
// occupancy 10% -> replace with our own grid-stride zero kernel.
//
// ws layout: agg[50000*64] f32 | offs[50000] i32 | eids[800000] i32  (~15.5 MB)

__device__ __forceinline__ float swish_f(float v) {
    return v / (1.0f + __expf(-v));
}

__global__ __launch_bounds__(256) void zero_kernel(int4* __restrict__ p, int n4)
{
    const int i = blockIdx.x * 256 + threadIdx.x;
    if (i < n4) p[i] = make_int4(0, 0, 0, 0);
}

__global__ __launch_bounds__(256) void hist_kernel(
    const int* __restrict__ col, int* __restrict__ cnt)
{
    const int e = blockIdx.x * 256 + threadIdx.x;
    if (e < N_EDGES) atomicAdd(&cnt[col[e]], 1);
}

// in-place counts -> exclusive starts. single block, 1024 threads, chunked.
__global__ __launch_bounds__(1024) void scan_kernel(int* __restrict__ offs)
{
    const int T = 1024;
    const int C = (N_NODES + T - 1) / T;   // 49
    const int t = threadIdx.x;
    const int base = t * C;

    int s = 0;
    for (int i = 0; i < C; ++i) {
        const int idx = base + i;
        if (idx < N_NODES) s += offs[idx];
    }
    __shared__ int sm[T];
    sm[t] = s;
    __syncthreads();
    for (int d = 1; d < T; d <<= 1) {
        const int v = (t >= d) ? sm[t - d] : 0;
        __syncthreads();
        sm[t] += v;
        __syncthreads();
    }
    int run = (t == 0) ? 0 : sm[t - 1];
    for (int i = 0; i < C; ++i) {
        const int idx = base + i;
        if (idx < N_NODES) {
            const int c = offs[idx];
            offs[idx] = run;
            run += c;
        }
    }
}

// offs[n] = start(n) on entry; on exit offs[n] = start(n)+count(n) = start(n+1).
// gather then uses beg = (n==0)?0:offs[n-1], end = offs[n].
__global__ __launch_bounds__(256) void fill_kernel(
    const int* __restrict__ col, int* __restrict__ offs, int* __restrict__ eids)
{
    const int e = blockIdx.x * 256 + threadIdx.x;
    if (e < N_EDGES) {
        const int c = col[e];
        const int pos = atomicAdd(&offs[c], 1);
        eids[pos] = e;
    }
}

// one wave per node: 16 lanes x float4 cover 64 dims; 4 edge-slots in parallel.
__global__ __launch_bounds__(256) void agg_kernel(
    const float* __restrict__ edge_attr,
    const int* __restrict__ offs,
    const int* __restrict__ eids,
    float* __restrict__ agg)
{
    const int n = (blockIdx.x * 256 + threadIdx.x) >> 6;
    if (n >= N_NODES) return;
    const int lane = threadIdx.x & 63;
    const int q = lane & 15;      // dim quad: dims [4q, 4q+4)
    const int slot = lane >> 4;   // edge slot 0..3
    const int beg = (n == 0) ? 0 : offs[n - 1];
    const int deg = offs[n] - beg;

    float4 acc = make_float4(0.f, 0.f, 0.f, 0.f);
    for (int i = slot; i < deg; i += 4) {
        const int eid = eids[beg + i];
        const float4 v = *reinterpret_cast<const float4*>(
            edge_attr + (size_t)eid * DD + q * 4);
        acc.x += v.x; acc.y += v.y; acc.z += v.z; acc.w += v.w;
    }
    #pragma unroll
    for (int m = 16; m < 64; m <<= 1) {
        acc.x += __shfl_xor(acc.x, m, 64);
        acc.y += __shfl_xor(acc.y, m, 64);
        acc.z += __shfl_xor(acc.z, m, 64);
        acc.w += __shfl_xor(acc.w, m, 64);
    }
    if (slot == 0)
        *reinterpret_cast<float4*>(agg + (size_t)n * DD + q * 4) = acc;
}

// ---------------- fused 2-layer MLP ----------------
__global__ __launch_bounds__(256) void mlp_kernel(
    const float* __restrict__ x,
    const float* __restrict__ agg,
    const float* __restrict__ u,
    const int* __restrict__ batch,
    const float* __restrict__ W1,
    const float* __restrict__ b1,
    const float* __restrict__ W2,
    const float* __restrict__ b2,
    float* __restrict__ out)
{
    __shared__ float sh[64][65];
    const int lane = threadIdx.x & 63;
    const int j0 = __builtin_amdgcn_readfirstlane((threadIdx.x >> 6) << 4);
    const int node = blockIdx.x * 64 + lane;
    const bool valid = node < N_NODES;
    const int nc = valid ? node : (N_NODES - 1);

    float acc[16];
    #pragma unroll
    for (int j = 0; j < 16; ++j) acc[j] = b1[j0 + j];

    const float* __restrict__ row0 = x + (size_t)nc * DD;
    const float* __restrict__ row1 = agg + (size_t)nc * DD;
    const float* __restrict__ row2 = u + (size_t)batch[nc] * DD;

    #pragma unroll
    for (int s = 0; s < 3; ++s) {
        const float* __restrict__ row = (s == 0) ? row0 : (s == 1) ? row1 : row2;
        const float* __restrict__ w = W1 + (size_t)s * 64 * 64 + j0;
        for (int kk = 0; kk < 64; kk += 4) {
            const float4 v = *reinterpret_cast<const float4*>(row + kk);
            #pragma unroll
            for (int i = 0; i < 4; ++i) {
                const float iv = (i == 0) ? v.x : (i == 1) ? v.y : (i == 2) ? v.z : v.w;
                const float* __restrict__ wr = w + (size_t)(kk + i) * 64;
                #pragma unroll
                for (int j = 0; j < 16; ++j)
                    acc[j] += iv * wr[j];
            }
        }
    }

    #pragma unroll
    for (int j = 0; j < 16; ++j)
        sh[lane][j0 + j] = swish_f(acc[j]);

    __syncthreads();

    float acc2[16];
    #pragma unroll
    for (int j = 0; j < 16; ++j) acc2[j] = b2[j0 + j];
    for (int k = 0; k < 64; ++k) {
        const float hk = sh[lane][k];
        const float* __restrict__ wr = W2 + (size_t)k * 64 + j0;
        #pragma unroll
        for (int j = 0; j < 16; ++j)
            acc2[j] += hk * wr[j];
    }

    if (valid) {
        float* o = out + (size_t)node * DD + j0;
        #pragma unroll
        for (int j = 0; j < 16; j += 4) {
            float4 r;
            r.x = swish_f(acc2[j + 0]);
            r.y = swish_f(acc2[j + 1]);
            r.z = swish_f(acc2[j + 2]);
            r.w = swish_f(acc2[j + 3]);
            *reinterpret_cast<float4*>(o + j) = r;
        }
    }
}

extern "C" void kernel_launch(void* const* d_in, const int* in_sizes, int n_in,
                              void* d_out, int out_size, void* d_ws, size_t ws_size,
                              hipStream_t stream) {
    const float* x         = (const float*)d_in[0];
    const int*   ei        = (const int*)d_in[1];
    const float* edge_attr = (const float*)d_in[2];
    const float* u         = (const float*)d_in[3];
    const int*   batch     = (const int*)d_in[4];
    const float* W1        = (const float*)d_in[5];
    const float* b1        = (const float*)d_in[6];
    const float* W2        = (const float*)d_in[7];
    const float* b2        = (const float*)d_in[8];
    float* out = (float*)d_out;

    float* agg = (float*)d_ws;
    int* offs  = (int*)((char*)d_ws + (size_t)N_NODES * DD * sizeof(float));
    int* eids  = offs + N_NODES;
    const int* col = ei + N_EDGES;   // edge_index[1]

    // zero offs (50000 ints, 12500 int4) with our own kernel:
    // R4 showed rocclr's small-fill kernel costs 117us for 200KB.
    zero_kernel<<<(12500 + 255) / 256, 256, 0, stream>>>((int4*)offs, 12500);

    hist_kernel<<<(N_EDGES + 255) / 256, 256, 0, stream>>>(col, offs);
    scan_kernel<<<1, 1024, 0, stream>>>(offs);
    fill_kernel<<<(N_EDGES + 255) / 256, 256, 0, stream>>>(col, offs, eids);
    agg_kernel<<<(N_NODES + 3) / 4, 256, 0, stream>>>(edge_attr, offs, eids, agg);

    mlp_kernel<<<(N_NODES + 63) / 64, 256, 0, stream>>>(x, agg, u, batch, W1, b1, W2, b2, out);
}